// Round 8
// baseline (980.109 us; speedup 1.0000x reference)
//
#include <hip/hip_runtime.h>
#include <hip/hip_fp16.h>

#define NN 100000
#define NE 1600000
#define CH 64
#define STEPS 10
#define ALPHA 0.1f
#define NG 8            // channel groups (one per XCD)
#define GCH 8           // channels per group; row = 8 bf16 = 16 B
#define WPG 6250        // waves per group = NN/16

#define SCAN_BLK 256
#define SCAN_ITEMS 4
#define SCAN_TILE (SCAN_BLK * SCAN_ITEMS)   // 1024
#define N_TILES ((NN + SCAN_TILE - 1) / SCAN_TILE)  // 98

typedef unsigned int uint;

// pack two f32 into bf16x2 word, RNE (low half = first arg)
__device__ inline uint pack_bf16x2(float x, float y) {
    uint ux = __float_as_uint(x);
    ux += 0x7FFFu + ((ux >> 16) & 1u);
    uint uy = __float_as_uint(y);
    uy += 0x7FFFu + ((uy >> 16) & 1u);
    return (ux >> 16) | (uy & 0xFFFF0000u);
}

// ---- histogram of dst ----
__global__ void k_count(const int* __restrict__ dst, int* __restrict__ cnt, int E) {
    int e = blockIdx.x * blockDim.x + threadIdx.x;
    if (e < E) atomicAdd(&cnt[dst[e]], 1);
}

// ---- dinv = rsqrt(max(deg,1)) ----
__global__ void k_dinv(const int* __restrict__ cnt, float* __restrict__ dinv, int n) {
    int i = blockIdx.x * blockDim.x + threadIdx.x;
    if (i < n) dinv[i] = rsqrtf(fmaxf((float)cnt[i], 1.0f));
}

// ---- scan phase 1: per-tile sums ----
__global__ void k_scan1(const int* __restrict__ cnt, int* __restrict__ tileSums, int n) {
    __shared__ int lds[SCAN_BLK];
    int base = blockIdx.x * SCAN_TILE + threadIdx.x * SCAN_ITEMS;
    int s = 0;
    #pragma unroll
    for (int j = 0; j < SCAN_ITEMS; ++j) { int i = base + j; if (i < n) s += cnt[i]; }
    lds[threadIdx.x] = s;
    __syncthreads();
    for (int off = SCAN_BLK / 2; off > 0; off >>= 1) {
        if (threadIdx.x < off) lds[threadIdx.x] += lds[threadIdx.x + off];
        __syncthreads();
    }
    if (threadIdx.x == 0) tileSums[blockIdx.x] = lds[0];
}

// ---- scan phase 2: exclusive scan of tile sums ----
__global__ void k_scan2(int* __restrict__ tileSums, int nTiles) {
    __shared__ int lds[256];
    int v = (threadIdx.x < nTiles) ? tileSums[threadIdx.x] : 0;
    lds[threadIdx.x] = v;
    __syncthreads();
    for (int off = 1; off < 256; off <<= 1) {
        int t = (threadIdx.x >= off) ? lds[threadIdx.x - off] : 0;
        __syncthreads();
        lds[threadIdx.x] += t;
        __syncthreads();
    }
    if (threadIdx.x < nTiles) tileSums[threadIdx.x] = lds[threadIdx.x] - v;
}

// ---- scan phase 3: per-tile exclusive scan + tile offset -> rowptr & cursor ----
__global__ void k_scan3(const int* __restrict__ cnt, const int* __restrict__ tileOffs,
                        int* __restrict__ rowptr, int* __restrict__ cursor, int n) {
    __shared__ int lds[SCAN_BLK];
    int base = blockIdx.x * SCAN_TILE + threadIdx.x * SCAN_ITEMS;
    int vals[SCAN_ITEMS];
    int s = 0;
    #pragma unroll
    for (int j = 0; j < SCAN_ITEMS; ++j) {
        int i = base + j;
        vals[j] = (i < n) ? cnt[i] : 0;
        s += vals[j];
    }
    lds[threadIdx.x] = s;
    __syncthreads();
    int inc = s;
    for (int off = 1; off < SCAN_BLK; off <<= 1) {
        int t = (threadIdx.x >= off) ? lds[threadIdx.x - off] : 0;
        __syncthreads();
        lds[threadIdx.x] += t;
        __syncthreads();
    }
    int excl = lds[threadIdx.x] - inc + tileOffs[blockIdx.x];
    #pragma unroll
    for (int j = 0; j < SCAN_ITEMS; ++j) {
        int i = base + j;
        if (i < n) { rowptr[i] = excl; cursor[i] = excl; excl += vals[j]; }
    }
    if (blockIdx.x == 0 && threadIdx.x == 0) rowptr[n] = NE;
}

// ---- CSR fill: 4 B record = (src << 15) | (f16(w) >> 1); w>0 so sign bit free ----
__global__ void k_fill(const int* __restrict__ src, const int* __restrict__ dst,
                       const float* __restrict__ dinv, int* __restrict__ cursor,
                       uint* __restrict__ rec, int E) {
    int e = blockIdx.x * blockDim.x + threadIdx.x;
    if (e < E) {
        int s = src[e], d = dst[e];
        float w = dinv[s] * dinv[d];
        unsigned short hb = __half_as_ushort(__float2half_rn(w));
        int pos = atomicAdd(&cursor[d], 1);
        rec[pos] = ((uint)s << 15) | (uint)(hb >> 1);
    }
}

// ---- transpose x (f32 [node][64]) -> xq (bf16 grouped [g][node][8]) ----
__global__ void k_xq(const float* __restrict__ x, uint4* __restrict__ xq) {
    int i = blockIdx.x * blockDim.x + threadIdx.x;   // [0, NN*NG)
    if (i >= NN * NG) return;
    int node = i >> 3, g = i & 7;
    const float4* xr = (const float4*)(x + (size_t)node * CH + g * GCH);
    float4 lo = xr[0];
    float4 hi = xr[1];
    uint4 o;
    o.x = pack_bf16x2(lo.x, lo.y);
    o.y = pack_bf16x2(lo.z, lo.w);
    o.z = pack_bf16x2(hi.x, hi.y);
    o.w = pack_bf16x2(hi.z, hi.w);
    xq[(size_t)g * NN + node] = o;
}

// ---- propagation, channel-grouped: group g = blockIdx%8 (XCD affinity).
//      wave = 16 nodes x 4 lanes; lane owns 2 bf16 channels of its node.
//      No cross-lane reduction. Edge loop in predicated batches of 4. ----
__global__ __launch_bounds__(256) void
k_prop(const int* __restrict__ rowptr, const uint* __restrict__ rec,
       const uint* __restrict__ hsrc, uint* __restrict__ hdst) {
    int g  = blockIdx.x & 7;
    int bg = blockIdx.x >> 3;
    int wid = bg * 4 + (threadIdx.x >> 6);
    if (wid >= WPG) return;
    int lane = threadIdx.x & 63;
    int ni = lane >> 2;          // node within wave
    int cl = lane & 3;           // uint slot within 16 B row (2 channels)
    int node = wid * 16 + ni;

    int base = rowptr[node];
    int endv = rowptr[node + 1];
    int safe = base < NE ? base : NE - 1;
    const uint* __restrict__ hrow = hsrc + (size_t)g * (NN * 4);

    float a0 = 0.f, a1 = 0.f;
    for (int off = 0; __any(base + off < endv); off += 4) {
        uint r[4];
        #pragma unroll
        for (int j = 0; j < 4; ++j) {
            int ix = base + off + j;
            r[j] = rec[ix < endv ? ix : safe];
        }
        uint hv[4];
        #pragma unroll
        for (int j = 0; j < 4; ++j) {
            int s = (int)(r[j] >> 15);
            hv[j] = hrow[(size_t)s * 4 + cl];
        }
        #pragma unroll
        for (int j = 0; j < 4; ++j) {
            int ix = base + off + j;
            float wt = (ix < endv)
                ? __half2float(__ushort_as_half((unsigned short)((r[j] & 0x7FFFu) << 1)))
                : 0.0f;
            a0 = fmaf(__uint_as_float(hv[j] << 16), wt, a0);
            a1 = fmaf(__uint_as_float(hv[j] & 0xFFFF0000u), wt, a1);
        }
    }
    hdst[((size_t)g * NN + node) * 4 + cl] = pack_bf16x2(a0, a1);
}

// ---- final: out = alpha*x + (1-alpha)/STEPS * sum_t h_t ----
__global__ void k_sum10(const uint* __restrict__ hbase, const float* __restrict__ x,
                        float* __restrict__ out) {
    int node = blockIdx.x * blockDim.x + threadIdx.x;
    int g = blockIdx.y;
    if (node >= NN) return;
    float s[8] = {0.f, 0.f, 0.f, 0.f, 0.f, 0.f, 0.f, 0.f};
    #pragma unroll
    for (int t = 0; t < STEPS; ++t) {
        const uint4* b = (const uint4*)(hbase + (size_t)t * (NG * NN * 4));
        uint4 v = b[(size_t)g * NN + node];
        s[0] += __uint_as_float(v.x << 16); s[1] += __uint_as_float(v.x & 0xFFFF0000u);
        s[2] += __uint_as_float(v.y << 16); s[3] += __uint_as_float(v.y & 0xFFFF0000u);
        s[4] += __uint_as_float(v.z << 16); s[5] += __uint_as_float(v.z & 0xFFFF0000u);
        s[6] += __uint_as_float(v.w << 16); s[7] += __uint_as_float(v.w & 0xFFFF0000u);
    }
    const float4* xr = (const float4*)(x + (size_t)node * CH + g * GCH);
    float4 xlo = xr[0], xhi = xr[1];
    float4* orow = (float4*)(out + (size_t)node * CH + g * GCH);
    float4 rlo, rhi;
    rlo.x = ALPHA * xlo.x + (1.0f - ALPHA) * (s[0] * (1.0f / STEPS));
    rlo.y = ALPHA * xlo.y + (1.0f - ALPHA) * (s[1] * (1.0f / STEPS));
    rlo.z = ALPHA * xlo.z + (1.0f - ALPHA) * (s[2] * (1.0f / STEPS));
    rlo.w = ALPHA * xlo.w + (1.0f - ALPHA) * (s[3] * (1.0f / STEPS));
    rhi.x = ALPHA * xhi.x + (1.0f - ALPHA) * (s[4] * (1.0f / STEPS));
    rhi.y = ALPHA * xhi.y + (1.0f - ALPHA) * (s[5] * (1.0f / STEPS));
    rhi.z = ALPHA * xhi.z + (1.0f - ALPHA) * (s[6] * (1.0f / STEPS));
    rhi.w = ALPHA * xhi.w + (1.0f - ALPHA) * (s[7] * (1.0f / STEPS));
    orow[0] = rlo;
    orow[1] = rhi;
}

extern "C" void kernel_launch(void* const* d_in, const int* in_sizes, int n_in,
                              void* d_out, int out_size, void* d_ws, size_t ws_size,
                              hipStream_t stream) {
    const float* x  = (const float*)d_in[0];
    const int*   ei = (const int*)d_in[1];     // [2, NE]: row0=src, row1=dst
    const int*   src = ei;
    const int*   dst = ei + NE;
    float* out = (float*)d_out;

    char* ws = (char*)d_ws;
    const size_t MB = 1024 * 1024;
    int*   cnt      = (int*)  (ws);                 // 400 KB
    float* dinv     = (float*)(ws + 1 * MB);        // 400 KB
    int*   rowptr   = (int*)  (ws + 2 * MB);        // 400 KB (+1)
    int*   cursor   = (int*)  (ws + 3 * MB);        // 400 KB
    int*   tileSums = (int*)  (ws + 4 * MB);        // <1 KB
    uint*  rec      = (uint*) (ws + 5 * MB);        // 6.4 MB
    uint*  hbase    = (uint*) (ws + 12 * MB);       // 10 x 12.8 MB = 128 MB

    uint* xq = (uint*)d_out;                        // first 12.8 MB of out; dead by sum10

    hipMemsetAsync(cnt, 0, NN * sizeof(int), stream);
    k_count<<<(NE + 255) / 256, 256, 0, stream>>>(dst, cnt, NE);
    k_dinv <<<(NN + 255) / 256, 256, 0, stream>>>(cnt, dinv, NN);
    k_scan1<<<N_TILES, SCAN_BLK, 0, stream>>>(cnt, tileSums, NN);
    k_scan2<<<1, 256, 0, stream>>>(tileSums, N_TILES);
    k_scan3<<<N_TILES, SCAN_BLK, 0, stream>>>(cnt, tileSums, rowptr, cursor, NN);
    k_fill <<<(NE + 255) / 256, 256, 0, stream>>>(src, dst, dinv, cursor, rec, NE);
    k_xq   <<<(NN * NG) / 256, 256, 0, stream>>>(x, (uint4*)xq);

    const size_t GSZ = (size_t)NG * NN * 4;         // uints per time-buffer
    const int blocksPerGroup = (WPG + 3) / 4;       // 1563
    const int propBlocks = NG * blocksPerGroup;     // 12504

    for (int t = 0; t < STEPS; ++t) {
        const uint* hsrc = (t == 0) ? xq : hbase + (size_t)(t - 1) * GSZ;
        uint* hdst = hbase + (size_t)t * GSZ;
        k_prop<<<propBlocks, 256, 0, stream>>>(rowptr, rec, hsrc, hdst);
    }

    dim3 sgrid((NN + 255) / 256, NG);
    k_sum10<<<sgrid, 256, 0, stream>>>(hbase, x, out);
}

// Round 9
// 571.736 us; speedup vs baseline: 1.7143x; 1.7143x over previous
//
#include <hip/hip_runtime.h>

#define NN 100000
#define NE 1600000
#define CH 64
#define STEPS 10
#define ALPHA 0.1f
#define NG 8                 // dst-range groups (one per XCD)
#define NPG (NN / NG)        // 12500 nodes per group
#define BPG 256              // edge-slice blocks per group
#define CHUNK (NE / BPG)     // 6250 edges per slice

#define SCAN_BLK 256
#define SCAN_ITEMS 4
#define SCAN_TILE (SCAN_BLK * SCAN_ITEMS)   // 1024
#define N_TILES ((NN + SCAN_TILE - 1) / SCAN_TILE)  // 98

typedef unsigned int uint;
typedef unsigned long long ull;

// pack two f32 into bf16x2 word, RNE (low half = first arg)
__device__ inline uint pack_bf16x2(float x, float y) {
    uint ux = __float_as_uint(x);
    ux += 0x7FFFu + ((ux >> 16) & 1u);
    uint uy = __float_as_uint(y);
    uy += 0x7FFFu + ((uy >> 16) & 1u);
    return (ux >> 16) | (uy & 0xFFFF0000u);
}

// ---- histogram of dst, dst-range partitioned: group g=blockIdx&7 owns
//      dst in [g*NPG,(g+1)*NPG) so cnt lines live on one XCD only ----
__global__ __launch_bounds__(256) void
k_count(const int* __restrict__ dst, int* __restrict__ cnt, int E) {
    int g  = blockIdx.x & (NG - 1);
    int s  = blockIdx.x >> 3;
    int lo = g * NPG, hi = lo + NPG;
    int send = s * CHUNK + CHUNK; if (send > E) send = E;
    for (int i = s * CHUNK + threadIdx.x; i < send; i += 256) {
        int d = dst[i];
        if (d >= lo && d < hi) atomicAdd(&cnt[d], 1);
    }
}

// ---- dinv = rsqrt(max(deg,1)) ----
__global__ void k_dinv(const int* __restrict__ cnt, float* __restrict__ dinv, int n) {
    int i = blockIdx.x * blockDim.x + threadIdx.x;
    if (i < n) dinv[i] = rsqrtf(fmaxf((float)cnt[i], 1.0f));
}

// ---- scan phase 1: per-tile sums ----
__global__ void k_scan1(const int* __restrict__ cnt, int* __restrict__ tileSums, int n) {
    __shared__ int lds[SCAN_BLK];
    int base = blockIdx.x * SCAN_TILE + threadIdx.x * SCAN_ITEMS;
    int s = 0;
    #pragma unroll
    for (int j = 0; j < SCAN_ITEMS; ++j) { int i = base + j; if (i < n) s += cnt[i]; }
    lds[threadIdx.x] = s;
    __syncthreads();
    for (int off = SCAN_BLK / 2; off > 0; off >>= 1) {
        if (threadIdx.x < off) lds[threadIdx.x] += lds[threadIdx.x + off];
        __syncthreads();
    }
    if (threadIdx.x == 0) tileSums[blockIdx.x] = lds[0];
}

// ---- scan phase 2: exclusive scan of tile sums ----
__global__ void k_scan2(int* __restrict__ tileSums, int nTiles) {
    __shared__ int lds[256];
    int v = (threadIdx.x < nTiles) ? tileSums[threadIdx.x] : 0;
    lds[threadIdx.x] = v;
    __syncthreads();
    for (int off = 1; off < 256; off <<= 1) {
        int t = (threadIdx.x >= off) ? lds[threadIdx.x - off] : 0;
        __syncthreads();
        lds[threadIdx.x] += t;
        __syncthreads();
    }
    if (threadIdx.x < nTiles) tileSums[threadIdx.x] = lds[threadIdx.x] - v;
}

// ---- scan phase 3: per-tile exclusive scan + tile offset -> rowptr & cursor ----
__global__ void k_scan3(const int* __restrict__ cnt, const int* __restrict__ tileOffs,
                        int* __restrict__ rowptr, int* __restrict__ cursor, int n) {
    __shared__ int lds[SCAN_BLK];
    int base = blockIdx.x * SCAN_TILE + threadIdx.x * SCAN_ITEMS;
    int vals[SCAN_ITEMS];
    int s = 0;
    #pragma unroll
    for (int j = 0; j < SCAN_ITEMS; ++j) {
        int i = base + j;
        vals[j] = (i < n) ? cnt[i] : 0;
        s += vals[j];
    }
    lds[threadIdx.x] = s;
    __syncthreads();
    int inc = s;
    for (int off = 1; off < SCAN_BLK; off <<= 1) {
        int t = (threadIdx.x >= off) ? lds[threadIdx.x - off] : 0;
        __syncthreads();
        lds[threadIdx.x] += t;
        __syncthreads();
    }
    int excl = lds[threadIdx.x] - inc + tileOffs[blockIdx.x];
    #pragma unroll
    for (int j = 0; j < SCAN_ITEMS; ++j) {
        int i = base + j;
        if (i < n) { rowptr[i] = excl; cursor[i] = excl; excl += vals[j]; }
    }
    if (blockIdx.x == 0 && threadIdx.x == 0) rowptr[n] = NE;
}

// ---- CSR fill, dst-range partitioned: group g writes ONLY its contiguous
//      pair span + its cursor slice (one XCD's L2); 8x edge re-read ----
__global__ __launch_bounds__(256) void
k_fill(const int* __restrict__ src, const int* __restrict__ dst,
       const float* __restrict__ dinv, int* __restrict__ cursor,
       int2* __restrict__ pair, int E) {
    int g  = blockIdx.x & (NG - 1);
    int s  = blockIdx.x >> 3;
    int lo = g * NPG, hi = lo + NPG;
    int send = s * CHUNK + CHUNK; if (send > E) send = E;
    for (int i = s * CHUNK + threadIdx.x; i < send; i += 256) {
        int d = dst[i];
        if (d >= lo && d < hi) {
            int sv = src[i];
            int pos = atomicAdd(&cursor[d], 1);
            pair[pos] = make_int2(sv, __float_as_int(dinv[sv] * dinv[d]));
        }
    }
}

// ---- propagation (round-7 verbatim): one wave per node; quarter-split:
//      q=lane>>4 owns edge slot, cl=lane&15 owns 4 channels (uint2 bf16 /
//      float4 f32). Batch 16 always + 8 predicated + rare loop. ----
template<bool SRCF32>
__global__ __launch_bounds__(256) void
k_prop(const int* __restrict__ rowptr, const int2* __restrict__ pair,
       const void* __restrict__ h, uint2* __restrict__ hn) {
    int wid  = (int)((blockIdx.x * (long long)blockDim.x + threadIdx.x) >> 6);
    int lane = threadIdx.x & 63;
    if (wid >= NN) return;
    int q  = lane >> 4;
    int cl = lane & 15;
    int start = rowptr[wid];
    int end   = rowptr[wid + 1];
    int safe  = start < NE ? start : NE - 1;
    const ull* pp = (const ull*)pair;

    float a0 = 0.f, a1 = 0.f, a2 = 0.f, a3 = 0.f;

    #define GATHER_FMA(PE, ACTIVE)                                               \
        {                                                                        \
            int   s_ = (int)(uint)(PE);                                          \
            float wt = (ACTIVE) ? __uint_as_float((uint)((PE) >> 32)) : 0.0f;    \
            if (SRCF32) {                                                        \
                float4 hv = ((const float4*)h)[(long long)s_ * 16 + cl];         \
                a0 = fmaf(hv.x, wt, a0); a1 = fmaf(hv.y, wt, a1);                \
                a2 = fmaf(hv.z, wt, a2); a3 = fmaf(hv.w, wt, a3);                \
            } else {                                                             \
                uint2 hv = ((const uint2*)h)[(long long)s_ * 16 + cl];           \
                a0 = fmaf(__uint_as_float(hv.x << 16),        wt, a0);           \
                a1 = fmaf(__uint_as_float(hv.x & 0xFFFF0000u), wt, a1);          \
                a2 = fmaf(__uint_as_float(hv.y << 16),        wt, a2);           \
                a3 = fmaf(__uint_as_float(hv.y & 0xFFFF0000u), wt, a3);          \
            }                                                                    \
        }

    {
        ull pe[4];
        #pragma unroll
        for (int j = 0; j < 4; ++j) {
            int ix = start + 4 * j + q;
            pe[j] = pp[ix < end ? ix : safe];
        }
        #pragma unroll
        for (int j = 0; j < 4; ++j) {
            int ix = start + 4 * j + q;
            GATHER_FMA(pe[j], ix < end);
        }
    }
    if (end > start + 16) {
        ull pe[2];
        #pragma unroll
        for (int j = 0; j < 2; ++j) {
            int ix = start + 16 + 4 * j + q;
            pe[j] = pp[ix < end ? ix : safe];
        }
        #pragma unroll
        for (int j = 0; j < 2; ++j) {
            int ix = start + 16 + 4 * j + q;
            GATHER_FMA(pe[j], ix < end);
        }
    }
    for (int p = start + 24; p < end; p += 4) {
        int ix = p + q;
        if (ix < end) {
            ull pe = pp[ix];
            GATHER_FMA(pe, true);
        }
    }
    #undef GATHER_FMA

    a0 += __shfl_xor(a0, 16); a1 += __shfl_xor(a1, 16);
    a2 += __shfl_xor(a2, 16); a3 += __shfl_xor(a3, 16);
    a0 += __shfl_xor(a0, 32); a1 += __shfl_xor(a1, 32);
    a2 += __shfl_xor(a2, 32); a3 += __shfl_xor(a3, 32);

    if (q == 0) {
        long long o = (long long)wid * 16 + cl;
        hn[o] = make_uint2(pack_bf16x2(a0, a1), pack_bf16x2(a2, a3));
    }
}

// ---- deferred combine: out = alpha*x + (1-alpha)/STEPS * sum_t h_t ----
__global__ void k_sum10(const uint2* __restrict__ hbase, const float* __restrict__ x,
                        float* __restrict__ out, int total) {
    int i = blockIdx.x * blockDim.x + threadIdx.x;
    if (i >= total) return;
    float s0 = 0.f, s1 = 0.f, s2 = 0.f, s3 = 0.f;
    #pragma unroll
    for (int t = 0; t < STEPS; ++t) {
        uint2 v = hbase[(size_t)t * (NN * 16) + i];
        s0 += __uint_as_float(v.x << 16);
        s1 += __uint_as_float(v.x & 0xFFFF0000u);
        s2 += __uint_as_float(v.y << 16);
        s3 += __uint_as_float(v.y & 0xFFFF0000u);
    }
    float4 xv = ((const float4*)x)[i];
    float4 r;
    r.x = ALPHA * xv.x + (1.0f - ALPHA) * (s0 * (1.0f / STEPS));
    r.y = ALPHA * xv.y + (1.0f - ALPHA) * (s1 * (1.0f / STEPS));
    r.z = ALPHA * xv.z + (1.0f - ALPHA) * (s2 * (1.0f / STEPS));
    r.w = ALPHA * xv.w + (1.0f - ALPHA) * (s3 * (1.0f / STEPS));
    ((float4*)out)[i] = r;
}

extern "C" void kernel_launch(void* const* d_in, const int* in_sizes, int n_in,
                              void* d_out, int out_size, void* d_ws, size_t ws_size,
                              hipStream_t stream) {
    const float* x  = (const float*)d_in[0];
    const int*   ei = (const int*)d_in[1];     // [2, NE]: row0=src, row1=dst
    const int*   src = ei;
    const int*   dst = ei + NE;
    float* out = (float*)d_out;

    char* ws = (char*)d_ws;
    const size_t MB = 1024 * 1024;
    int*   cnt      = (int*)  (ws);                 // 400 KB
    float* dinv     = (float*)(ws + 1 * MB);        // 400 KB
    int*   rowptr   = (int*)  (ws + 2 * MB);        // 400 KB (+1)
    int*   cursor   = (int*)  (ws + 3 * MB);        // 400 KB
    int*   tileSums = (int*)  (ws + 4 * MB);        // <1 KB
    int2*  pair     = (int2*) (ws + 5 * MB);        // 12.8 MB
    uint2* hbase    = (uint2*)(ws + 20 * MB);       // 10 x 12.8 MB = 128 MB

    const size_t HBUF = (size_t)NN * 16;            // uint2 per h buffer

    hipMemsetAsync(cnt, 0, NN * sizeof(int), stream);
    k_count<<<NG * BPG, 256, 0, stream>>>(dst, cnt, NE);
    k_dinv <<<(NN + 255) / 256, 256, 0, stream>>>(cnt, dinv, NN);
    k_scan1<<<N_TILES, SCAN_BLK, 0, stream>>>(cnt, tileSums, NN);
    k_scan2<<<1, 256, 0, stream>>>(tileSums, N_TILES);
    k_scan3<<<N_TILES, SCAN_BLK, 0, stream>>>(cnt, tileSums, rowptr, cursor, NN);
    k_fill <<<NG * BPG, 256, 0, stream>>>(src, dst, dinv, cursor, pair, NE);

    const int propBlocks = (NN * 64 + 255) / 256;   // one wave per node

    const void* hcur = (const void*)x;
    for (int t = 0; t < STEPS; ++t) {
        uint2* hn = hbase + (size_t)t * HBUF;
        if (t == 0)
            k_prop<true ><<<propBlocks, 256, 0, stream>>>(rowptr, pair, hcur, hn);
        else
            k_prop<false><<<propBlocks, 256, 0, stream>>>(rowptr, pair, hcur, hn);
        hcur = (const void*)hn;
    }

    const int total = NN * 16;
    k_sum10<<<(total + 255) / 256, 256, 0, stream>>>(hbase, x, out, total);
}

// Round 10
// 532.673 us; speedup vs baseline: 1.8400x; 1.0733x over previous
//
#include <hip/hip_runtime.h>

#define NN 100000
#define NE 1600000
#define CH 64
#define STEPS 10
#define ALPHA 0.1f

#define BW 256                       // nodes per bucket
#define NB ((NN + BW - 1) / BW)      // 391 buckets
#define PBLK 256                     // partition blocks
#define PCHUNK (NE / PBLK)           // 6250 edges per partition block
#define CAPB 6144                    // LDS record capacity in phase B

typedef unsigned int uint;
typedef unsigned long long ull;

// pack two f32 into bf16x2 word, RNE (low half = first arg)
__device__ inline uint pack_bf16x2(float x, float y) {
    uint ux = __float_as_uint(x);
    ux += 0x7FFFu + ((ux >> 16) & 1u);
    uint uy = __float_as_uint(y);
    uy += 0x7FFFu + ((uy >> 16) & 1u);
    return (ux >> 16) | (uy & 0xFFFF0000u);
}

// ---- histogram of dst (simple; atomic-bound but only ~6% of total) ----
__global__ void k_count(const int* __restrict__ dst, int* __restrict__ cnt, int E) {
    int e = blockIdx.x * blockDim.x + threadIdx.x;
    if (e < E) atomicAdd(&cnt[dst[e]], 1);
}

// ---- dinv = rsqrt(max(deg,1)) ----
__global__ void k_dinv(const int* __restrict__ cnt, float* __restrict__ dinv, int n) {
    int i = blockIdx.x * blockDim.x + threadIdx.x;
    if (i < n) dinv[i] = rsqrtf(fmaxf((float)cnt[i], 1.0f));
}

// ---- per-bucket sums of cnt ----
__global__ void k_bsum(const int* __restrict__ cnt, int* __restrict__ bcnt) {
    __shared__ int lds[256];
    int node = blockIdx.x * 256 + threadIdx.x;
    lds[threadIdx.x] = (node < NN) ? cnt[node] : 0;
    __syncthreads();
    for (int off = 128; off > 0; off >>= 1) {
        if (threadIdx.x < off) lds[threadIdx.x] += lds[threadIdx.x + off];
        __syncthreads();
    }
    if (threadIdx.x == 0) bcnt[blockIdx.x] = lds[0];
}

// ---- exclusive scan of 391 bucket sums (single 512-thread block) ----
__global__ void k_scanb(const int* __restrict__ bcnt, int* __restrict__ bbase,
                        int* __restrict__ gcur) {
    __shared__ int lds[512];
    int tid = threadIdx.x;
    int v = (tid < NB) ? bcnt[tid] : 0;
    lds[tid] = v;
    __syncthreads();
    for (int off = 1; off < 512; off <<= 1) {
        int t = (tid >= off) ? lds[tid - off] : 0;
        __syncthreads();
        lds[tid] += t;
        __syncthreads();
    }
    int excl = lds[tid] - v;
    if (tid < NB) { bbase[tid] = excl; gcur[tid] = excl; }
    if (tid == 0) bbase[NB] = NE;
}

// ---- phase A: partition edges into dst-buckets; dense run-reserved writes ----
// record: x = src | (dst_local << 17), y = w (f32)
__global__ __launch_bounds__(256) void
k_partA(const int* __restrict__ src, const int* __restrict__ dst,
        const float* __restrict__ dinv, int* __restrict__ gcur,
        int2* __restrict__ tmp) {
    __shared__ int hist[NB];
    __shared__ int gbase[NB];
    __shared__ int lcur[NB];
    int tid = threadIdx.x;
    for (int i = tid; i < NB; i += 256) hist[i] = 0;
    __syncthreads();
    int s0 = blockIdx.x * PCHUNK;
    for (int i = s0 + tid; i < s0 + PCHUNK; i += 256)
        atomicAdd(&hist[dst[i] >> 8], 1);
    __syncthreads();
    for (int b = tid; b < NB; b += 256) {
        int h = hist[b];
        gbase[b] = (h > 0) ? atomicAdd(&gcur[b], h) : 0;
        lcur[b] = 0;
    }
    __syncthreads();
    for (int i = s0 + tid; i < s0 + PCHUNK; i += 256) {
        int d = dst[i];
        int sv = src[i];
        int b = d >> 8;
        float w = dinv[sv] * dinv[d];
        int r = atomicAdd(&lcur[b], 1);
        tmp[gbase[b] + r] = make_int2(sv | ((d & 255) << 17), __float_as_int(w));
    }
}

// ---- phase B: sort one bucket in LDS by dst; build rowptr; stream out ----
__global__ __launch_bounds__(256) void
k_partB(const int* __restrict__ cnt, const int* __restrict__ bbase,
        const int2* __restrict__ tmp, int2* __restrict__ pair,
        int* __restrict__ rowptr) {
    __shared__ int2 recs[CAPB];
    __shared__ int lofs[256];
    __shared__ int lcur[256];
    int b = blockIdx.x, tid = threadIdx.x;
    int nb0 = b * BW;
    int nodes = (NN - nb0 < BW) ? (NN - nb0) : BW;
    int base = bbase[b];
    int m = bbase[b + 1] - base;

    // block scan of cnt slice -> rowptr + local cursors
    int v = (tid < nodes) ? cnt[nb0 + tid] : 0;
    lofs[tid] = v;
    __syncthreads();
    for (int off = 1; off < 256; off <<= 1) {
        int t = (tid >= off) ? lofs[tid - off] : 0;
        __syncthreads();
        lofs[tid] += t;
        __syncthreads();
    }
    int excl = lofs[tid] - v;
    if (tid < nodes) { rowptr[nb0 + tid] = base + excl; lcur[tid] = excl; }
    if (b == 0 && tid == 0) rowptr[NN] = NE;
    __syncthreads();

    if (m <= CAPB) {
        for (int i = tid; i < m; i += 256) {
            int2 r = tmp[base + i];
            int dl = (r.x >> 17) & 255;
            int p = atomicAdd(&lcur[dl], 1);
            recs[p] = make_int2(r.x & 0x1FFFF, r.y);
        }
        __syncthreads();
        for (int i = tid; i < m; i += 256)
            pair[base + i] = recs[i];
    } else {
        // overflow fallback: direct global scatter (L2-local span)
        for (int i = tid; i < m; i += 256) {
            int2 r = tmp[base + i];
            int dl = (r.x >> 17) & 255;
            int p = atomicAdd(&lcur[dl], 1);
            pair[base + p] = make_int2(r.x & 0x1FFFF, r.y);
        }
    }
}

// ---- propagation (round-7 verbatim): one wave per node; quarter-split:
//      q=lane>>4 owns edge slot, cl=lane&15 owns 4 channels (uint2 bf16 /
//      float4 f32). Batch 16 always + 8 predicated + rare loop. ----
template<bool SRCF32>
__global__ __launch_bounds__(256) void
k_prop(const int* __restrict__ rowptr, const int2* __restrict__ pair,
       const void* __restrict__ h, uint2* __restrict__ hn) {
    int wid  = (int)((blockIdx.x * (long long)blockDim.x + threadIdx.x) >> 6);
    int lane = threadIdx.x & 63;
    if (wid >= NN) return;
    int q  = lane >> 4;
    int cl = lane & 15;
    int start = rowptr[wid];
    int end   = rowptr[wid + 1];
    int safe  = start < NE ? start : NE - 1;
    const ull* pp = (const ull*)pair;

    float a0 = 0.f, a1 = 0.f, a2 = 0.f, a3 = 0.f;

    #define GATHER_FMA(PE, ACTIVE)                                               \
        {                                                                        \
            int   s_ = (int)(uint)(PE);                                          \
            float wt = (ACTIVE) ? __uint_as_float((uint)((PE) >> 32)) : 0.0f;    \
            if (SRCF32) {                                                        \
                float4 hv = ((const float4*)h)[(long long)s_ * 16 + cl];         \
                a0 = fmaf(hv.x, wt, a0); a1 = fmaf(hv.y, wt, a1);                \
                a2 = fmaf(hv.z, wt, a2); a3 = fmaf(hv.w, wt, a3);                \
            } else {                                                             \
                uint2 hv = ((const uint2*)h)[(long long)s_ * 16 + cl];           \
                a0 = fmaf(__uint_as_float(hv.x << 16),        wt, a0);           \
                a1 = fmaf(__uint_as_float(hv.x & 0xFFFF0000u), wt, a1);          \
                a2 = fmaf(__uint_as_float(hv.y << 16),        wt, a2);           \
                a3 = fmaf(__uint_as_float(hv.y & 0xFFFF0000u), wt, a3);          \
            }                                                                    \
        }

    {
        ull pe[4];
        #pragma unroll
        for (int j = 0; j < 4; ++j) {
            int ix = start + 4 * j + q;
            pe[j] = pp[ix < end ? ix : safe];
        }
        #pragma unroll
        for (int j = 0; j < 4; ++j) {
            int ix = start + 4 * j + q;
            GATHER_FMA(pe[j], ix < end);
        }
    }
    if (end > start + 16) {
        ull pe[2];
        #pragma unroll
        for (int j = 0; j < 2; ++j) {
            int ix = start + 16 + 4 * j + q;
            pe[j] = pp[ix < end ? ix : safe];
        }
        #pragma unroll
        for (int j = 0; j < 2; ++j) {
            int ix = start + 16 + 4 * j + q;
            GATHER_FMA(pe[j], ix < end);
        }
    }
    for (int p = start + 24; p < end; p += 4) {
        int ix = p + q;
        if (ix < end) {
            ull pe = pp[ix];
            GATHER_FMA(pe, true);
        }
    }
    #undef GATHER_FMA

    a0 += __shfl_xor(a0, 16); a1 += __shfl_xor(a1, 16);
    a2 += __shfl_xor(a2, 16); a3 += __shfl_xor(a3, 16);
    a0 += __shfl_xor(a0, 32); a1 += __shfl_xor(a1, 32);
    a2 += __shfl_xor(a2, 32); a3 += __shfl_xor(a3, 32);

    if (q == 0) {
        long long o = (long long)wid * 16 + cl;
        hn[o] = make_uint2(pack_bf16x2(a0, a1), pack_bf16x2(a2, a3));
    }
}

// ---- deferred combine: out = alpha*x + (1-alpha)/STEPS * sum_t h_t ----
__global__ void k_sum10(const uint2* __restrict__ hbase, const float* __restrict__ x,
                        float* __restrict__ out, int total) {
    int i = blockIdx.x * blockDim.x + threadIdx.x;
    if (i >= total) return;
    float s0 = 0.f, s1 = 0.f, s2 = 0.f, s3 = 0.f;
    #pragma unroll
    for (int t = 0; t < STEPS; ++t) {
        uint2 v = hbase[(size_t)t * (NN * 16) + i];
        s0 += __uint_as_float(v.x << 16);
        s1 += __uint_as_float(v.x & 0xFFFF0000u);
        s2 += __uint_as_float(v.y << 16);
        s3 += __uint_as_float(v.y & 0xFFFF0000u);
    }
    float4 xv = ((const float4*)x)[i];
    float4 r;
    r.x = ALPHA * xv.x + (1.0f - ALPHA) * (s0 * (1.0f / STEPS));
    r.y = ALPHA * xv.y + (1.0f - ALPHA) * (s1 * (1.0f / STEPS));
    r.z = ALPHA * xv.z + (1.0f - ALPHA) * (s2 * (1.0f / STEPS));
    r.w = ALPHA * xv.w + (1.0f - ALPHA) * (s3 * (1.0f / STEPS));
    ((float4*)out)[i] = r;
}

extern "C" void kernel_launch(void* const* d_in, const int* in_sizes, int n_in,
                              void* d_out, int out_size, void* d_ws, size_t ws_size,
                              hipStream_t stream) {
    const float* x  = (const float*)d_in[0];
    const int*   ei = (const int*)d_in[1];     // [2, NE]: row0=src, row1=dst
    const int*   src = ei;
    const int*   dst = ei + NE;
    float* out = (float*)d_out;

    char* ws = (char*)d_ws;
    const size_t MB = 1024 * 1024;
    const size_t KB = 1024;
    int*   cnt    = (int*)  (ws);                     // 400 KB
    float* dinv   = (float*)(ws + 1 * MB);            // 400 KB
    int*   rowptr = (int*)  (ws + 2 * MB);            // 400 KB (+1)
    int*   bcnt   = (int*)  (ws + 3 * MB);            // ~1.6 KB
    int*   bbase  = (int*)  (ws + 3 * MB + 64 * KB);  // ~1.6 KB (+1)
    int*   gcur   = (int*)  (ws + 3 * MB + 128 * KB); // ~1.6 KB
    int2*  pair   = (int2*) (ws + 5 * MB);            // 12.8 MB (final CSR)
    uint2* hbase  = (uint2*)(ws + 20 * MB);           // 10 x 12.8 MB = 128 MB
    int2*  tmp    = (int2*) (ws + 20 * MB);           // phase-A temp (dead before prop 0)

    const size_t HBUF = (size_t)NN * 16;              // uint2 per h buffer

    hipMemsetAsync(cnt, 0, NN * sizeof(int), stream);
    k_count<<<(NE + 255) / 256, 256, 0, stream>>>(dst, cnt, NE);
    k_dinv <<<(NN + 255) / 256, 256, 0, stream>>>(cnt, dinv, NN);
    k_bsum <<<NB, 256, 0, stream>>>(cnt, bcnt);
    k_scanb<<<1, 512, 0, stream>>>(bcnt, bbase, gcur);
    k_partA<<<PBLK, 256, 0, stream>>>(src, dst, dinv, gcur, tmp);
    k_partB<<<NB, 256, 0, stream>>>(cnt, bbase, tmp, pair, rowptr);

    const int propBlocks = (NN * 64 + 255) / 256;     // one wave per node

    const void* hcur = (const void*)x;
    for (int t = 0; t < STEPS; ++t) {
        uint2* hn = hbase + (size_t)t * HBUF;
        if (t == 0)
            k_prop<true ><<<propBlocks, 256, 0, stream>>>(rowptr, pair, hcur, hn);
        else
            k_prop<false><<<propBlocks, 256, 0, stream>>>(rowptr, pair, hcur, hn);
        hcur = (const void*)hn;
    }

    const int total = NN * 16;
    k_sum10<<<(total + 255) / 256, 256, 0, stream>>>(hbase, x, out, total);
}

// Round 11
// 473.762 us; speedup vs baseline: 2.0688x; 1.1243x over previous
//
#include <hip/hip_runtime.h>

#define NN 100000
#define NE 1600000
#define CH 64
#define STEPS 10
#define ALPHA 0.1f

#define BW 256                       // nodes per bucket
#define NB ((NN + BW - 1) / BW)      // 391 buckets
#define PBLK 256                     // partition blocks
#define PCHUNK (NE / PBLK)           // 6250 edges per partition block

typedef unsigned int uint;
typedef unsigned long long ull;

// pack two f32 into bf16x2 word, RNE (low half = first arg)
__device__ inline uint pack_bf16x2(float x, float y) {
    uint ux = __float_as_uint(x);
    ux += 0x7FFFu + ((ux >> 16) & 1u);
    uint uy = __float_as_uint(y);
    uy += 0x7FFFu + ((uy >> 16) & 1u);
    return (ux >> 16) | (uy & 0xFFFF0000u);
}

// ---- phase 1: per-block LDS bucket histogram -> dense histAll write ----
__global__ __launch_bounds__(256) void
k_hist(const int* __restrict__ dst, int* __restrict__ histAll) {
    __shared__ int hist[NB];
    int tid = threadIdx.x;
    for (int i = tid; i < NB; i += 256) hist[i] = 0;
    __syncthreads();
    int s0 = blockIdx.x * PCHUNK;
    for (int i = s0 + tid; i < s0 + PCHUNK; i += 256)
        atomicAdd(&hist[dst[i] >> 8], 1);
    __syncthreads();
    for (int b = tid; b < NB; b += 256)
        histAll[blockIdx.x * NB + b] = hist[b];
}

// ---- phase 2a: per-bucket scan over blocks: histAll -> excl offsets, bcnt ----
__global__ __launch_bounds__(256) void
k_colscan(int* __restrict__ histAll, int* __restrict__ bcnt) {
    __shared__ int lds[256];
    int b = blockIdx.x, tid = threadIdx.x;
    int v = histAll[tid * NB + b];
    lds[tid] = v;
    __syncthreads();
    for (int off = 1; off < 256; off <<= 1) {
        int t = (tid >= off) ? lds[tid - off] : 0;
        __syncthreads();
        lds[tid] += t;
        __syncthreads();
    }
    histAll[tid * NB + b] = lds[tid] - v;     // exclusive within bucket
    if (tid == 255) bcnt[b] = lds[255];
}

// ---- phase 2b: exclusive scan of 391 bucket sums -> bbase ----
__global__ void k_scanb(const int* __restrict__ bcnt, int* __restrict__ bbase) {
    __shared__ int lds[512];
    int tid = threadIdx.x;
    int v = (tid < NB) ? bcnt[tid] : 0;
    lds[tid] = v;
    __syncthreads();
    for (int off = 1; off < 512; off <<= 1) {
        int t = (tid >= off) ? lds[tid - off] : 0;
        __syncthreads();
        lds[tid] += t;
        __syncthreads();
    }
    if (tid < NB) bbase[tid] = lds[tid] - v;
    if (tid == 0) bbase[NB] = NE;
}

// ---- phase 3: scatter 4B records (src | dl<<17) into reserved dense runs ----
__global__ __launch_bounds__(256) void
k_partA2(const int* __restrict__ src, const int* __restrict__ dst,
         const int* __restrict__ histAll, const int* __restrict__ bbase,
         uint* __restrict__ tmp) {
    __shared__ int gb[NB];
    __shared__ int lcur[NB];
    int tid = threadIdx.x;
    for (int b = tid; b < NB; b += 256) {
        gb[b] = bbase[b] + histAll[blockIdx.x * NB + b];
        lcur[b] = 0;
    }
    __syncthreads();
    int s0 = blockIdx.x * PCHUNK;
    for (int i = s0 + tid; i < s0 + PCHUNK; i += 256) {
        int d = dst[i];
        int b = d >> 8;
        int r = atomicAdd(&lcur[b], 1);
        tmp[gb[b] + r] = (uint)src[i] | ((uint)(d & 255) << 17);
    }
}

// ---- phase 4: per-bucket degree histogram -> dinv + rowptr (dense writes) ----
__global__ __launch_bounds__(256) void
k_partB1(const uint* __restrict__ tmp, const int* __restrict__ bbase,
         float* __restrict__ dinv, int* __restrict__ rowptr) {
    __shared__ int hist[256];
    __shared__ int lds[256];
    int b = blockIdx.x, tid = threadIdx.x;
    int nb0 = b * BW;
    int nodes = (NN - nb0 < BW) ? (NN - nb0) : BW;
    int base = bbase[b];
    int m = bbase[b + 1] - base;
    hist[tid] = 0;
    __syncthreads();
    for (int i = tid; i < m; i += 256)
        atomicAdd(&hist[(tmp[base + i] >> 17) & 255], 1);
    __syncthreads();
    int v = hist[tid];
    lds[tid] = v;
    __syncthreads();
    for (int off = 1; off < 256; off <<= 1) {
        int t = (tid >= off) ? lds[tid - off] : 0;
        __syncthreads();
        lds[tid] += t;
        __syncthreads();
    }
    if (tid < nodes) {
        dinv[nb0 + tid] = rsqrtf(fmaxf((float)v, 1.0f));
        rowptr[nb0 + tid] = base + lds[tid] - v;
    }
    if (b == 0 && tid == 0) rowptr[NN] = NE;
}

// ---- phase 5: per-bucket sort-by-dst + weight -> final pair (L2-local span) ----
__global__ __launch_bounds__(256) void
k_partB2(const uint* __restrict__ tmp, const int* __restrict__ bbase,
         const float* __restrict__ dinv, int2* __restrict__ pair) {
    __shared__ int hist[256];
    __shared__ int lds[256];
    __shared__ int lcur[256];
    int b = blockIdx.x, tid = threadIdx.x;
    int nb0 = b * BW;
    int base = bbase[b];
    int m = bbase[b + 1] - base;
    hist[tid] = 0;
    __syncthreads();
    for (int i = tid; i < m; i += 256)
        atomicAdd(&hist[(tmp[base + i] >> 17) & 255], 1);
    __syncthreads();
    int v = hist[tid];
    lds[tid] = v;
    __syncthreads();
    for (int off = 1; off < 256; off <<= 1) {
        int t = (tid >= off) ? lds[tid - off] : 0;
        __syncthreads();
        lds[tid] += t;
        __syncthreads();
    }
    lcur[tid] = lds[tid] - v;     // exclusive offset within bucket
    __syncthreads();
    for (int i = tid; i < m; i += 256) {
        uint r = tmp[base + i];
        int dl = (r >> 17) & 255;
        int sv = (int)(r & 0x1FFFFu);
        float w = dinv[sv] * dinv[nb0 + dl];
        int p = atomicAdd(&lcur[dl], 1);
        pair[base + p] = make_int2(sv, __float_as_int(w));
    }
}

// ---- propagation (verbatim): one wave per node; quarter-split:
//      q=lane>>4 owns edge slot, cl=lane&15 owns 4 channels (uint2 bf16 /
//      float4 f32). Batch 16 always + 8 predicated + rare loop. ----
template<bool SRCF32>
__global__ __launch_bounds__(256) void
k_prop(const int* __restrict__ rowptr, const int2* __restrict__ pair,
       const void* __restrict__ h, uint2* __restrict__ hn) {
    int wid  = (int)((blockIdx.x * (long long)blockDim.x + threadIdx.x) >> 6);
    int lane = threadIdx.x & 63;
    if (wid >= NN) return;
    int q  = lane >> 4;
    int cl = lane & 15;
    int start = rowptr[wid];
    int end   = rowptr[wid + 1];
    int safe  = start < NE ? start : NE - 1;
    const ull* pp = (const ull*)pair;

    float a0 = 0.f, a1 = 0.f, a2 = 0.f, a3 = 0.f;

    #define GATHER_FMA(PE, ACTIVE)                                               \
        {                                                                        \
            int   s_ = (int)(uint)(PE);                                          \
            float wt = (ACTIVE) ? __uint_as_float((uint)((PE) >> 32)) : 0.0f;    \
            if (SRCF32) {                                                        \
                float4 hv = ((const float4*)h)[(long long)s_ * 16 + cl];         \
                a0 = fmaf(hv.x, wt, a0); a1 = fmaf(hv.y, wt, a1);                \
                a2 = fmaf(hv.z, wt, a2); a3 = fmaf(hv.w, wt, a3);                \
            } else {                                                             \
                uint2 hv = ((const uint2*)h)[(long long)s_ * 16 + cl];           \
                a0 = fmaf(__uint_as_float(hv.x << 16),        wt, a0);           \
                a1 = fmaf(__uint_as_float(hv.x & 0xFFFF0000u), wt, a1);          \
                a2 = fmaf(__uint_as_float(hv.y << 16),        wt, a2);           \
                a3 = fmaf(__uint_as_float(hv.y & 0xFFFF0000u), wt, a3);          \
            }                                                                    \
        }

    {
        ull pe[4];
        #pragma unroll
        for (int j = 0; j < 4; ++j) {
            int ix = start + 4 * j + q;
            pe[j] = pp[ix < end ? ix : safe];
        }
        #pragma unroll
        for (int j = 0; j < 4; ++j) {
            int ix = start + 4 * j + q;
            GATHER_FMA(pe[j], ix < end);
        }
    }
    if (end > start + 16) {
        ull pe[2];
        #pragma unroll
        for (int j = 0; j < 2; ++j) {
            int ix = start + 16 + 4 * j + q;
            pe[j] = pp[ix < end ? ix : safe];
        }
        #pragma unroll
        for (int j = 0; j < 2; ++j) {
            int ix = start + 16 + 4 * j + q;
            GATHER_FMA(pe[j], ix < end);
        }
    }
    for (int p = start + 24; p < end; p += 4) {
        int ix = p + q;
        if (ix < end) {
            ull pe = pp[ix];
            GATHER_FMA(pe, true);
        }
    }
    #undef GATHER_FMA

    a0 += __shfl_xor(a0, 16); a1 += __shfl_xor(a1, 16);
    a2 += __shfl_xor(a2, 16); a3 += __shfl_xor(a3, 16);
    a0 += __shfl_xor(a0, 32); a1 += __shfl_xor(a1, 32);
    a2 += __shfl_xor(a2, 32); a3 += __shfl_xor(a3, 32);

    if (q == 0) {
        long long o = (long long)wid * 16 + cl;
        hn[o] = make_uint2(pack_bf16x2(a0, a1), pack_bf16x2(a2, a3));
    }
}

// ---- deferred combine: out = alpha*x + (1-alpha)/STEPS * sum_t h_t ----
__global__ void k_sum10(const uint2* __restrict__ hbase, const float* __restrict__ x,
                        float* __restrict__ out, int total) {
    int i = blockIdx.x * blockDim.x + threadIdx.x;
    if (i >= total) return;
    float s0 = 0.f, s1 = 0.f, s2 = 0.f, s3 = 0.f;
    #pragma unroll
    for (int t = 0; t < STEPS; ++t) {
        uint2 v = hbase[(size_t)t * (NN * 16) + i];
        s0 += __uint_as_float(v.x << 16);
        s1 += __uint_as_float(v.x & 0xFFFF0000u);
        s2 += __uint_as_float(v.y << 16);
        s3 += __uint_as_float(v.y & 0xFFFF0000u);
    }
    float4 xv = ((const float4*)x)[i];
    float4 r;
    r.x = ALPHA * xv.x + (1.0f - ALPHA) * (s0 * (1.0f / STEPS));
    r.y = ALPHA * xv.y + (1.0f - ALPHA) * (s1 * (1.0f / STEPS));
    r.z = ALPHA * xv.z + (1.0f - ALPHA) * (s2 * (1.0f / STEPS));
    r.w = ALPHA * xv.w + (1.0f - ALPHA) * (s3 * (1.0f / STEPS));
    ((float4*)out)[i] = r;
}

extern "C" void kernel_launch(void* const* d_in, const int* in_sizes, int n_in,
                              void* d_out, int out_size, void* d_ws, size_t ws_size,
                              hipStream_t stream) {
    const float* x  = (const float*)d_in[0];
    const int*   ei = (const int*)d_in[1];     // [2, NE]: row0=src, row1=dst
    const int*   src = ei;
    const int*   dst = ei + NE;
    float* out = (float*)d_out;

    char* ws = (char*)d_ws;
    const size_t MB = 1024 * 1024;
    const size_t KB = 1024;
    int*   histAll = (int*)  (ws);                     // 256*391*4 ~ 400 KB
    float* dinv    = (float*)(ws + 1 * MB);            // 400 KB
    int*   rowptr  = (int*)  (ws + 2 * MB);            // 400 KB (+1)
    int*   bcnt    = (int*)  (ws + 3 * MB);            // ~1.6 KB
    int*   bbase   = (int*)  (ws + 3 * MB + 64 * KB);  // ~1.6 KB (+1)
    int2*  pair    = (int2*) (ws + 5 * MB);            // 12.8 MB (final CSR)
    uint2* hbase   = (uint2*)(ws + 20 * MB);           // 10 x 12.8 MB = 128 MB
    uint*  tmp     = (uint*) (ws + 20 * MB);           // 6.4 MB (dead before prop 0)

    const size_t HBUF = (size_t)NN * 16;               // uint2 per h buffer

    k_hist   <<<PBLK, 256, 0, stream>>>(dst, histAll);
    k_colscan<<<NB, 256, 0, stream>>>(histAll, bcnt);
    k_scanb  <<<1, 512, 0, stream>>>(bcnt, bbase);
    k_partA2 <<<PBLK, 256, 0, stream>>>(src, dst, histAll, bbase, tmp);
    k_partB1 <<<NB, 256, 0, stream>>>(tmp, bbase, dinv, rowptr);
    k_partB2 <<<NB, 256, 0, stream>>>(tmp, bbase, dinv, pair);

    const int propBlocks = (NN * 64 + 255) / 256;      // one wave per node

    const void* hcur = (const void*)x;
    for (int t = 0; t < STEPS; ++t) {
        uint2* hn = hbase + (size_t)t * HBUF;
        if (t == 0)
            k_prop<true ><<<propBlocks, 256, 0, stream>>>(rowptr, pair, hcur, hn);
        else
            k_prop<false><<<propBlocks, 256, 0, stream>>>(rowptr, pair, hcur, hn);
        hcur = (const void*)hn;
    }

    const int total = NN * 16;
    k_sum10<<<(total + 255) / 256, 256, 0, stream>>>(hbase, x, out, total);
}